// Round 3
// baseline (251.649 us; speedup 1.0000x reference)
//
#include <hip/hip_runtime.h>
#include <hip/hip_bf16.h>

#define SEQ 256
#define BATCH 4096
#define DD 100            // D = 2*hidden
#define SB (BATCH * DD)   // stride between seq steps, in floats
#define NFRAG 28          // 7 n-tiles * 4 k-tiles of W
#define WTOT (NFRAG * 64) // uint4 entries in packed W

typedef __attribute__((ext_vector_type(8))) short bf16x8;
typedef __attribute__((ext_vector_type(4))) float f32x4;

__device__ __forceinline__ short f2bf(float x) {
    __hip_bfloat16 h = __float2bfloat16(x);
    return *reinterpret_cast<short*>(&h);
}
__device__ __forceinline__ float bf2f(short s) {
    unsigned int u = ((unsigned int)(unsigned short)s) << 16;
    return __builtin_bit_cast(float, u);
}
__device__ __forceinline__ float fast_tanh(float x) {
    float ax = fabsf(x);
    float e  = __expf(-2.0f * ax);
    float t  = (1.0f - e) * __builtin_amdgcn_rcpf(1.0f + e);
    return copysignf(t, x);
}

// ---- prep: pack W [DD x DD] fp32 into MFMA B-fragments, bf16, zero-padded ----
// frag (n,t): cols [16n,16n+16), k [32t,32t+32). lane l: col = 16n+(l&15),
// k = 32t + 8*(l>>4) + e  -> one uint4 per lane. (verified round 2)
__global__ void prep_wfrag(const float* __restrict__ W, uint4* __restrict__ wsf) {
    const int idx = blockIdx.x * 256 + threadIdx.x;
    if (idx >= WTOT) return;
    const int l  = idx & 63;
    const int ft = idx >> 6;
    const int t  = ft & 3;
    const int n  = ft >> 2;
    const int col   = 16 * n + (l & 15);
    const int kbase = 32 * t + 8 * (l >> 4);
    unsigned short v[8];
    #pragma unroll
    for (int e = 0; e < 8; ++e) {
        const int k = kbase + e;
        const float w = (col < DD && k < DD) ? W[k * DD + col] : 0.0f;
        v[e] = (unsigned short)f2bf(w);
    }
    uint4 u;
    u.x = (unsigned)v[0] | ((unsigned)v[1] << 16);
    u.y = (unsigned)v[2] | ((unsigned)v[3] << 16);
    u.z = (unsigned)v[4] | ((unsigned)v[5] << 16);
    u.w = (unsigned)v[6] | ((unsigned)v[7] << 16);
    wsf[ft * 64 + l] = u;
}

__global__ __launch_bounds__(512, 4)
void fused_sent_attn(const float* __restrict__ f,     // [SEQ, BATCH, DD]
                     const uint4* __restrict__ wsf,   // packed W frags
                     const float* __restrict__ bias,  // [DD]
                     const float* __restrict__ cw,    // [DD]
                     const float* __restrict__ h,     // [2, BATCH, 50]
                     float* __restrict__ out)         // [pooled | h]
{
    __shared__ uint4  wlds[WTOT];      // 28672 B
    __shared__ float  bias_s[112];
    __shared__ float  cw_s[112];
    __shared__ float  sc[SEQ];
    __shared__ float  pool[8][DD];
    __shared__ float  red[8];

    const int b    = blockIdx.x;
    const int tid  = threadIdx.x;
    const int lane = tid & 63;
    const int wid  = tid >> 6;
    const int lr   = lane & 15;    // A-row-in-tile / C-col-in-tile
    const int g    = lane >> 4;    // k-group

    // ---- stage W frags + bias/cw into LDS (sources are L2/L3-resident) ----
    #pragma unroll
    for (int k = 0; k < 4; ++k) {
        const int i = tid + 512 * k;
        if (i < WTOT) wlds[i] = wsf[i];
    }
    if (tid < 112) {
        bias_s[tid] = (tid < DD) ? bias[tid] : 0.0f;
        cw_s[tid]   = (tid < DD) ? cw[tid]   : 0.0f;
    }

    // ---- A-fragments: 2 rows of f per lane (32 rows/wave), bf16, K 100->128 ----
    bf16x8 a[2][4];
    #pragma unroll
    for (int m = 0; m < 2; ++m) {
        const float* frow = f + (size_t)(32 * wid + 16 * m + lr) * SB + (size_t)b * DD;
        float4 st[7];
        #pragma unroll
        for (int j = 0; j < 6; ++j)
            st[j] = *reinterpret_cast<const float4*>(frow + 32 * (j >> 1) + 8 * g + 4 * (j & 1));
        st[6] = *reinterpret_cast<const float4*>(frow + 96);   // broadcast per row
        #pragma unroll
        for (int t = 0; t < 3; ++t) {
            bf16x8 av;
            av[0] = f2bf(st[2*t].x);   av[1] = f2bf(st[2*t].y);
            av[2] = f2bf(st[2*t].z);   av[3] = f2bf(st[2*t].w);
            av[4] = f2bf(st[2*t+1].x); av[5] = f2bf(st[2*t+1].y);
            av[6] = f2bf(st[2*t+1].z); av[7] = f2bf(st[2*t+1].w);
            a[m][t] = av;
        }
        bf16x8 av3 = {0, 0, 0, 0, 0, 0, 0, 0};
        if (g == 0) {                  // k 96..99 valid, 100..127 zero
            av3[0] = f2bf(st[6].x); av3[1] = f2bf(st[6].y);
            av3[2] = f2bf(st[6].z); av3[3] = f2bf(st[6].w);
        }
        a[m][3] = av3;
    }

    // ---- h passthrough folded in (waves 4-5) ----
    if (tid >= 256 && tid < 356) {
        const int j = tid - 256;
        const size_t HB = (size_t)BATCH * 50;
        const size_t obase = (size_t)BATCH * DD;
        if (j < 50)
            out[obase + (size_t)b * 50 + j] = h[(size_t)b * 50 + j];
        else
            out[obase + HB + (size_t)b * 50 + (j - 50)] = h[HB + (size_t)b * 50 + (j - 50)];
    }

    __syncthreads();

    // ---- U = tanh(F W + bias); scp += tanh(u) * cw ----
    float scp[2][4] = {{0, 0, 0, 0}, {0, 0, 0, 0}};
    #pragma unroll
    for (int n = 0; n < 7; ++n) {
        const int coln = 16 * n + lr;
        const float bias_v = bias_s[coln];
        const float cw_v   = cw_s[coln];
        bf16x8 bfr[4];
        #pragma unroll
        for (int t = 0; t < 4; ++t)
            bfr[t] = *reinterpret_cast<const bf16x8*>(&wlds[(n * 4 + t) * 64 + lane]);
        f32x4 acc0 = {bias_v, bias_v, bias_v, bias_v};
        f32x4 acc1 = acc0;
        #pragma unroll
        for (int t = 0; t < 4; ++t) {
            acc0 = __builtin_amdgcn_mfma_f32_16x16x32_bf16(a[0][t], bfr[t], acc0, 0, 0, 0);
            acc1 = __builtin_amdgcn_mfma_f32_16x16x32_bf16(a[1][t], bfr[t], acc1, 0, 0, 0);
        }
        #pragma unroll
        for (int r = 0; r < 4; ++r) {
            scp[0][r] = fmaf(fast_tanh(acc0[r]), cw_v, scp[0][r]);
            scp[1][r] = fmaf(fast_tanh(acc1[r]), cw_v, scp[1][r]);
        }
    }

    // ---- reduce over the 16 col-lanes, final tanh, publish scores ----
    #pragma unroll
    for (int m = 0; m < 2; ++m)
        #pragma unroll
        for (int r = 0; r < 4; ++r) {
            float v = scp[m][r];
            v += __shfl_xor(v, 1);
            v += __shfl_xor(v, 2);
            v += __shfl_xor(v, 4);
            v += __shfl_xor(v, 8);
            if (lr == 0) sc[32 * wid + 16 * m + 4 * g + r] = fast_tanh(v);
        }
    __syncthreads();

    // ---- softmax over s = 256 (waves 0-3) ----
    float p = 0.0f, score = 0.0f;
    if (tid < SEQ) {
        score = sc[tid];
        float mx = score;
        #pragma unroll
        for (int off = 32; off >= 1; off >>= 1)
            mx = fmaxf(mx, __shfl_xor(mx, off));
        if (lane == 0) red[wid] = mx;
    }
    __syncthreads();
    const float mx = fmaxf(fmaxf(red[0], red[1]), fmaxf(red[2], red[3]));
    if (tid < SEQ) {
        p = __expf(score - mx);
        float ssum = p;
        #pragma unroll
        for (int off = 32; off >= 1; off >>= 1)
            ssum += __shfl_xor(ssum, off);
        if (lane == 0) red[4 + wid] = ssum;
    }
    __syncthreads();
    if (tid < SEQ) {
        const float denom = red[4] + red[5] + red[6] + red[7];
        sc[tid] = p / denom;                 // attn[s]
    }
    __syncthreads();

    // ---- pooled[d] = sum_s attn[s] * f[s,d] from register A-frags ----
    const float aw0 = sc[32 * wid + lr];
    const float aw1 = sc[32 * wid + 16 + lr];
    #pragma unroll
    for (int t = 0; t < 4; ++t)
        #pragma unroll
        for (int e = 0; e < 8; ++e) {
            float v = fmaf(aw0, bf2f(a[0][t][e]), aw1 * bf2f(a[1][t][e]));
            v += __shfl_xor(v, 1);
            v += __shfl_xor(v, 2);
            v += __shfl_xor(v, 4);
            v += __shfl_xor(v, 8);
            if (lr == 0) {
                const int d = 32 * t + 8 * g + e;
                if (d < DD) pool[wid][d] = v;
            }
        }
    __syncthreads();

    if (tid < DD) {
        float s = 0.0f;
        #pragma unroll
        for (int w = 0; w < 8; ++w) s += pool[w][tid];
        out[(size_t)b * DD + tid] = s;
    }
}

extern "C" void kernel_launch(void* const* d_in, const int* in_sizes, int n_in,
                              void* d_out, int out_size, void* d_ws, size_t ws_size,
                              hipStream_t stream) {
    const float* f    = (const float*)d_in[0];   // [256, 4096, 100]
    const float* h    = (const float*)d_in[1];   // [2, 4096, 50]
    const float* W    = (const float*)d_in[2];   // [100, 100]
    const float* bias = (const float*)d_in[3];   // [1, 100]
    const float* cw   = (const float*)d_in[4];   // [100, 1]
    float* out = (float*)d_out;                  // [pooled 409600 | h 409600]

    uint4* wsf = (uint4*)d_ws;                   // 28672 B

    prep_wfrag<<<7, 256, 0, stream>>>(W, wsf);
    fused_sent_attn<<<BATCH, 512, 0, stream>>>(f, wsf, bias, cw, h, out);
}

// Round 4
// 229.177 us; speedup vs baseline: 1.0981x; 1.0981x over previous
//
#include <hip/hip_runtime.h>
#include <hip/hip_bf16.h>

#define SEQ 256
#define BATCH 4096
#define DD 100              // D = 2*hidden
#define SB (BATCH * DD)     // seq stride in floats
#define NB 16               // batch columns per persistent block
#define LROW 104            // bf16 elems per LDS row (208 B, 16B-aligned)
#define NFRAG 28            // 7 n-tiles * 4 k-tiles of W
#define WTOT (NFRAG * 64)

typedef __attribute__((ext_vector_type(8))) short bf16x8;
typedef __attribute__((ext_vector_type(4))) float f32x4;

__device__ __forceinline__ unsigned short f2bf_u(float x) {
    __hip_bfloat16 h = __float2bfloat16(x);
    return *reinterpret_cast<unsigned short*>(&h);
}
__device__ __forceinline__ float bfbits2f(unsigned int hi_bits) {
    return __builtin_bit_cast(float, hi_bits);
}
__device__ __forceinline__ float fast_tanh(float x) {
    float ax = fabsf(x);
    float e  = __expf(-2.0f * ax);
    float t  = (1.0f - e) * __builtin_amdgcn_rcpf(1.0f + e);
    return copysignf(t, x);
}

// ---- prep: pack W [DD x DD] fp32 -> MFMA B-fragments (bf16, zero-padded) ----
// frag (n,t): cols [16n,16n+16), k [32t,32t+32). lane l: col = 16n+(l&15),
// k = 32t + 8*(l>>4) + e. Layout verified rounds 2-3.
__global__ void prep_wfrag(const float* __restrict__ W, uint4* __restrict__ wsf) {
    const int idx = blockIdx.x * 256 + threadIdx.x;
    if (idx >= WTOT) return;
    const int l  = idx & 63;
    const int ft = idx >> 6;
    const int t  = ft & 3;
    const int n  = ft >> 2;
    const int col   = 16 * n + (l & 15);
    const int kbase = 32 * t + 8 * (l >> 4);
    unsigned short v[8];
    #pragma unroll
    for (int e = 0; e < 8; ++e) {
        const int k = kbase + e;
        const float w = (col < DD && k < DD) ? W[k * DD + col] : 0.0f;
        v[e] = f2bf_u(w);
    }
    uint4 u;
    u.x = (unsigned)v[0] | ((unsigned)v[1] << 16);
    u.y = (unsigned)v[2] | ((unsigned)v[3] << 16);
    u.z = (unsigned)v[4] | ((unsigned)v[5] << 16);
    u.w = (unsigned)v[6] | ((unsigned)v[7] << 16);
    wsf[ft * 64 + l] = u;
}

__global__ __launch_bounds__(512, 2)
void fused_sent_attn(const float* __restrict__ f,     // [SEQ, BATCH, DD]
                     const uint4* __restrict__ wsf,   // packed W frags
                     const float* __restrict__ bias,  // [DD]
                     const float* __restrict__ cw,    // [DD]
                     const float* __restrict__ h,     // [2, BATCH, 50]
                     float* __restrict__ out)         // [pooled | h]
{
    __shared__ unsigned short fs[2][SEQ][LROW];   // 106,496 B (bf16 tiles)
    __shared__ uint4 wlds[WTOT];                  // 28,672 B
    __shared__ float sc[SEQ];                     // raw scores
    __shared__ float pool_s[16][DD];              // 6,400 B

    const int tid  = threadIdx.x;
    const int lane = tid & 63;
    const int wid  = tid >> 6;
    const int lr   = lane & 15;
    const int g    = lane >> 4;
    const int b0   = blockIdx.x * NB;

    // ---- prologue: W frags -> LDS; bias/cw -> per-lane regs; h passthrough ----
    for (int i = tid; i < WTOT; i += 512) wlds[i] = wsf[i];

    float bias_r[7], cw_r[7];
    #pragma unroll
    for (int n = 0; n < 7; ++n) {
        const int c = 16 * n + lr;
        bias_r[n] = (c < DD) ? bias[c] : 0.0f;
        cw_r[n]   = (c < DD) ? cw[c]   : 0.0f;
    }

    {
        const size_t obase = (size_t)BATCH * DD;
        const size_t HB = (size_t)BATCH * 50;
        for (int i = tid; i < 2 * NB * 50; i += 512) {
            const int half = i / (NB * 50);
            const int rem  = i - half * (NB * 50);
            const int c    = rem / 50;
            const int k    = rem - c * 50;
            const size_t src = half * HB + (size_t)(b0 + c) * 50 + k;
            out[obase + src] = h[src];
        }
    }

    // ---- prologue: stage tile for column b0 into buf 0 ----
    {
        float4 rv[13];
        #pragma unroll
        for (int r = 0; r < 13; ++r) {
            const int i = tid + 512 * r;
            if (i < 6400) {
                const int row = i / 25;
                const int c4  = i - row * 25;
                rv[r] = *reinterpret_cast<const float4*>(
                    f + (size_t)row * SB + (size_t)b0 * DD + 4 * c4);
            }
        }
        #pragma unroll
        for (int r = 0; r < 13; ++r) {
            const int i = tid + 512 * r;
            if (i < 6400) {
                const int row = i / 25;
                const int c4  = i - row * 25;
                uint2 pk;
                pk.x = (unsigned)f2bf_u(rv[r].x) | ((unsigned)f2bf_u(rv[r].y) << 16);
                pk.y = (unsigned)f2bf_u(rv[r].z) | ((unsigned)f2bf_u(rv[r].w) << 16);
                *reinterpret_cast<uint2*>(&fs[0][row][4 * c4]) = pk;
            }
        }
    }
    __syncthreads();

    int cur = 0;
    for (int j = 0; j < NB; ++j) {
        const int b = b0 + j;
        const bool pf = (j + 1 < NB);

        // ---- 1. issue prefetch loads for column b+1 (values used only at step 5) ----
        float4 rv[13];
        if (pf) {
            #pragma unroll
            for (int r = 0; r < 13; ++r) {
                const int i = tid + 512 * r;
                if (i < 6400) {
                    const int row = i / 25;
                    const int c4  = i - row * 25;
                    rv[r] = *reinterpret_cast<const float4*>(
                        f + (size_t)row * SB + (size_t)(b + 1) * DD + 4 * c4);
                }
            }
        }

        // ---- 2. scores: A-frags from LDS, MFMA, tanh epilogue ----
        const unsigned short* fsc = &fs[cur][0][0];
        bf16x8 a[2][4];
        #pragma unroll
        for (int m = 0; m < 2; ++m) {
            const int row = 32 * wid + 16 * m + lr;
            const unsigned short* rp = fsc + row * LROW;
            #pragma unroll
            for (int t = 0; t < 3; ++t)
                a[m][t] = *reinterpret_cast<const bf16x8*>(rp + 32 * t + 8 * g);
            bf16x8 a3 = {0, 0, 0, 0, 0, 0, 0, 0};
            if (g == 0) {                     // k 96..99 valid; rest of K padded zero
                const uint2 q2 = *reinterpret_cast<const uint2*>(rp + 96);
                a3[0] = (short)(q2.x & 0xffff); a3[1] = (short)(q2.x >> 16);
                a3[2] = (short)(q2.y & 0xffff); a3[3] = (short)(q2.y >> 16);
            }
            a[m][3] = a3;
        }

        float scp[2][4] = {{0, 0, 0, 0}, {0, 0, 0, 0}};
        #pragma unroll
        for (int n = 0; n < 7; ++n) {
            bf16x8 bfr[4];
            #pragma unroll
            for (int t = 0; t < 4; ++t)
                bfr[t] = *reinterpret_cast<const bf16x8*>(&wlds[(4 * n + t) * 64 + lane]);
            f32x4 acc0 = {bias_r[n], bias_r[n], bias_r[n], bias_r[n]};
            f32x4 acc1 = acc0;
            #pragma unroll
            for (int t = 0; t < 4; ++t) {
                acc0 = __builtin_amdgcn_mfma_f32_16x16x32_bf16(a[0][t], bfr[t], acc0, 0, 0, 0);
                acc1 = __builtin_amdgcn_mfma_f32_16x16x32_bf16(a[1][t], bfr[t], acc1, 0, 0, 0);
            }
            #pragma unroll
            for (int r = 0; r < 4; ++r) {
                scp[0][r] = fmaf(fast_tanh(acc0[r]), cw_r[n], scp[0][r]);
                scp[1][r] = fmaf(fast_tanh(acc1[r]), cw_r[n], scp[1][r]);
            }
        }
        #pragma unroll
        for (int m = 0; m < 2; ++m)
            #pragma unroll
            for (int r = 0; r < 4; ++r) {
                float v = scp[m][r];
                v += __shfl_xor(v, 1);
                v += __shfl_xor(v, 2);
                v += __shfl_xor(v, 4);
                v += __shfl_xor(v, 8);
                if (lr == 0) sc[32 * wid + 16 * m + 4 * g + r] = fast_tanh(v);
            }
        __syncthreads();   // B1: sc ready (prefetch loads still in flight / returned)

        // ---- 3. per-wave softmax denom (scores in [-1,1] -> no max pass needed) ----
        float e4 = __expf(sc[lane]) + __expf(sc[lane + 64])
                 + __expf(sc[lane + 128]) + __expf(sc[lane + 192]);
        #pragma unroll
        for (int off = 32; off >= 1; off >>= 1)
            e4 += __shfl_xor(e4, off);
        const float rdenom = 1.0f / e4;

        // ---- 4. pooling from LDS tile ----
        const int q  = tid & 31;     // d-quad
        const int sg = tid >> 5;     // s-group of 16
        if (q < 25) {
            f32x4 acc = {0, 0, 0, 0};
            #pragma unroll
            for (int i = 0; i < 16; ++i) {
                const int s = 16 * sg + i;
                const float att = __expf(sc[s]) * rdenom;
                const uint2 pk = *reinterpret_cast<const uint2*>(&fs[cur][s][4 * q]);
                acc.x = fmaf(att, bfbits2f(pk.x << 16),          acc.x);
                acc.y = fmaf(att, bfbits2f(pk.x & 0xffff0000u),  acc.y);
                acc.z = fmaf(att, bfbits2f(pk.y << 16),          acc.z);
                acc.w = fmaf(att, bfbits2f(pk.y & 0xffff0000u),  acc.w);
            }
            *reinterpret_cast<f32x4*>(&pool_s[sg][4 * q]) = acc;
        }

        // ---- 5. write prefetched tile -> buf[cur^1] (vmcnt drains here) ----
        if (pf) {
            #pragma unroll
            for (int r = 0; r < 13; ++r) {
                const int i = tid + 512 * r;
                if (i < 6400) {
                    const int row = i / 25;
                    const int c4  = i - row * 25;
                    uint2 pk;
                    pk.x = (unsigned)f2bf_u(rv[r].x) | ((unsigned)f2bf_u(rv[r].y) << 16);
                    pk.y = (unsigned)f2bf_u(rv[r].z) | ((unsigned)f2bf_u(rv[r].w) << 16);
                    *reinterpret_cast<uint2*>(&fs[cur ^ 1][row][4 * c4]) = pk;
                }
            }
        }
        __syncthreads();   // B2: pool_s + next tile ready; cur-tile readers done

        // ---- 6. final reduce + out write ----
        if (tid < DD) {
            float s = 0.0f;
            #pragma unroll
            for (int g2 = 0; g2 < 16; ++g2) s += pool_s[g2][tid];
            out[(size_t)b * DD + tid] = s;
        }
        cur ^= 1;
    }
}

extern "C" void kernel_launch(void* const* d_in, const int* in_sizes, int n_in,
                              void* d_out, int out_size, void* d_ws, size_t ws_size,
                              hipStream_t stream) {
    const float* f    = (const float*)d_in[0];   // [256, 4096, 100]
    const float* h    = (const float*)d_in[1];   // [2, 4096, 50]
    const float* W    = (const float*)d_in[2];   // [100, 100]
    const float* bias = (const float*)d_in[3];   // [1, 100]
    const float* cw   = (const float*)d_in[4];   // [100, 1]
    float* out = (float*)d_out;                  // [pooled 409600 | h 409600]

    uint4* wsf = (uint4*)d_ws;                   // 28,672 B

    prep_wfrag<<<7, 256, 0, stream>>>(W, wsf);
    fused_sent_attn<<<BATCH / NB, 512, 0, stream>>>(f, wsf, bias, cw, h, out);
}

// Round 5
// 205.832 us; speedup vs baseline: 1.2226x; 1.1134x over previous
//
#include <hip/hip_runtime.h>
#include <hip/hip_bf16.h>

#define SEQ 256
#define BATCH 4096
#define DD 100
#define SB (BATCH * DD)        // floats between s-planes
#define NBCOL 8                // batch columns per block
#define SCH 16                 // s per chunk
#define NCHUNK (SEQ / SCH)     // 16
#define ROWS (SCH * NBCOL)     // 128 rows per chunk (row = s_local*8 + b_local)
#define LROW 104               // bf16 elems per LDS row (208 B, 16B-aligned)
#define CH_F4 (ROWS * DD / 4)  // 3200 float4 per chunk

typedef __attribute__((ext_vector_type(8))) short bf16x8;
typedef __attribute__((ext_vector_type(4))) float f32x4;

__device__ __forceinline__ unsigned short f2bf_u(float x) {
    __hip_bfloat16 hv = __float2bfloat16(x);
    return *reinterpret_cast<unsigned short*>(&hv);
}
__device__ __forceinline__ float bf2f_lo(unsigned int u) {   // low 16 bits -> float
    return __builtin_bit_cast(float, u << 16);
}
__device__ __forceinline__ float bf2f_hi(unsigned int u) {   // high 16 bits -> float
    return __builtin_bit_cast(float, u & 0xffff0000u);
}
__device__ __forceinline__ float fast_tanh(float x) {
    float ax = fabsf(x);
    float e  = __expf(-2.0f * ax);
    float t  = (1.0f - e) * __builtin_amdgcn_rcpf(1.0f + e);
    return copysignf(t, x);
}

// ---- prep: pack W [DD x DD] fp32 -> MFMA B-fragments (bf16, zero-padded) ----
// frag (n,t): cols [16n,16n+16), k [32t,32t+32). lane l: col = 16n+(l&15),
// k = 32t + 8*(l>>4) + e. Layout verified rounds 2-4.
__global__ void prep_wfrag(const float* __restrict__ W, uint4* __restrict__ wsf) {
    const int idx = blockIdx.x * 256 + threadIdx.x;
    if (idx >= 28 * 64) return;
    const int l  = idx & 63;
    const int ft = idx >> 6;
    const int t  = ft & 3;
    const int n  = ft >> 2;
    const int col   = 16 * n + (l & 15);
    const int kbase = 32 * t + 8 * (l >> 4);
    unsigned short v[8];
    #pragma unroll
    for (int e = 0; e < 8; ++e) {
        const int k = kbase + e;
        const float w = (col < DD && k < DD) ? W[k * DD + col] : 0.0f;
        v[e] = f2bf_u(w);
    }
    uint4 u;
    u.x = (unsigned)v[0] | ((unsigned)v[1] << 16);
    u.y = (unsigned)v[2] | ((unsigned)v[3] << 16);
    u.z = (unsigned)v[4] | ((unsigned)v[5] << 16);
    u.w = (unsigned)v[6] | ((unsigned)v[7] << 16);
    wsf[ft * 64 + l] = u;
}

__global__ __launch_bounds__(512, 4)
void fused_sent_attn(const float* __restrict__ f,     // [SEQ, BATCH, DD]
                     const uint4* __restrict__ wsf,   // packed W frags (28*64)
                     const float* __restrict__ bias,  // [DD]
                     const float* __restrict__ cw,    // [DD]
                     const float* __restrict__ h,     // [2, BATCH, 50]
                     float* __restrict__ out)         // [pooled | h]
{
    __shared__ unsigned short fs[2][ROWS][LROW];   // 53,248 B
    __shared__ uint4 wlds[21 * 64];                // 21,504 B (t = 0..2 full frags)
    __shared__ uint4 wlds3[7 * 16];                // 1,792 B  (t = 3, lanes 0..15 only)
    __shared__ float wexp[ROWS];                   // 512 B
    __shared__ float den_s[NBCOL];                 // 32 B

    const int tid  = threadIdx.x;
    const int lane = tid & 63;
    const int wid  = tid >> 6;
    const int lr   = lane & 15;
    const int g    = lane >> 4;
    const int b0   = blockIdx.x * NBCOL;

    // ---- prologue: W frags -> LDS ----
    #pragma unroll
    for (int r = 0; r < 3; ++r) {
        const int i = tid + 512 * r;
        if (i < 21 * 64) {
            const int n = i / 192, rem = i % 192;
            wlds[i] = wsf[(4 * n + rem / 64) * 64 + (rem & 63)];
        }
    }
    if (tid < 7 * 16) wlds3[tid] = wsf[(4 * (tid >> 4) + 3) * 64 + (tid & 15)];

    // bias / cw per-lane registers (col = 16n + lr)
    float bias_r[7], cw_r[7];
    #pragma unroll
    for (int n = 0; n < 7; ++n) {
        const int c = 16 * n + lr;
        bias_r[n] = (c < DD) ? bias[c] : 0.0f;
        cw_r[n]   = (c < DD) ? cw[c]   : 0.0f;
    }

    // h passthrough for this block's 8 columns
    {
        const size_t obase = (size_t)BATCH * DD;
        const size_t HB = (size_t)BATCH * 50;
        for (int i = tid; i < 2 * NBCOL * 50; i += 512) {
            const int half = i / (NBCOL * 50);
            const int rem  = i - half * (NBCOL * 50);
            const size_t src = half * HB + (size_t)(b0 + rem / 50) * 50 + rem % 50;
            out[obase + src] = h[src];
        }
    }

    // zero pad elems 100..103 of every row, both buffers (never overwritten)
    if (tid < 2 * ROWS) {
        const int buf = tid >> 7, row = tid & (ROWS - 1);
        *reinterpret_cast<uint2*>(&fs[buf][row][100]) = make_uint2(0u, 0u);
    }

    // ---- stage chunk 0 ----
    {
        float4 rv[7];
        #pragma unroll
        for (int r = 0; r < 7; ++r) {
            const int i = tid + 512 * r;
            if (r < 6 || tid < CH_F4 - 512 * 6) {
                const int s = i / 200, piece = i - 200 * s;
                rv[r] = *reinterpret_cast<const float4*>(
                    f + (size_t)s * SB + (size_t)b0 * DD + 4 * piece);
            }
        }
        #pragma unroll
        for (int r = 0; r < 7; ++r) {
            const int i = tid + 512 * r;
            if (r < 6 || tid < CH_F4 - 512 * 6) {
                const int s = i / 200, piece = i - 200 * s;
                const int bl = piece / 25, c4 = piece - 25 * bl;
                uint2 pk;
                pk.x = (unsigned)f2bf_u(rv[r].x) | ((unsigned)f2bf_u(rv[r].y) << 16);
                pk.y = (unsigned)f2bf_u(rv[r].z) | ((unsigned)f2bf_u(rv[r].w) << 16);
                *reinterpret_cast<uint2*>(&fs[0][s * NBCOL + bl][4 * c4]) = pk;
            }
        }
    }
    __syncthreads();

    float acc0 = 0.0f, acc1 = 0.0f;     // pooled numerator, 2 (b,d) slots/thread
    float dreg = 0.0f;                  // denominator partial (threads 0..7)
    const int p0 = 2 * tid;             // pair base: b = p0/100, d = p0%100 (even)
    const int pb = p0 / 100, pd = p0 - 100 * pb;
    const bool pact = (tid < (NBCOL * DD) / 2);   // 400 active pooling threads

    int cur = 0;
    for (int jc = 0; jc < NCHUNK; ++jc) {
        const bool pf = (jc + 1 < NCHUNK);
        const int s_next = (jc + 1) * SCH;

        // ---- 1. issue next-chunk loads (consumed at step 5) ----
        float4 rv[7];
        if (pf) {
            #pragma unroll
            for (int r = 0; r < 7; ++r) {
                const int i = tid + 512 * r;
                if (r < 6 || tid < CH_F4 - 512 * 6) {
                    const int s = i / 200, piece = i - 200 * s;
                    rv[r] = *reinterpret_cast<const float4*>(
                        f + (size_t)(s_next + s) * SB + (size_t)b0 * DD + 4 * piece);
                }
            }
        }

        // ---- 2. scores for this chunk: wave w owns rows 16w..16w+15 ----
        {
            const unsigned short* rp = &fs[cur][16 * wid + lr][0];
            bf16x8 a[3];
            #pragma unroll
            for (int t = 0; t < 3; ++t)
                a[t] = *reinterpret_cast<const bf16x8*>(rp + 32 * t + 8 * g);
            bf16x8 a3 = {0, 0, 0, 0, 0, 0, 0, 0};
            if (g == 0) a3 = *reinterpret_cast<const bf16x8*>(rp + 96);

            float scp[4] = {0, 0, 0, 0};
            #pragma unroll
            for (int n = 0; n < 7; ++n) {
                bf16x8 bfr[3];
                #pragma unroll
                for (int t = 0; t < 3; ++t)
                    bfr[t] = *reinterpret_cast<const bf16x8*>(&wlds[(3 * n + t) * 64 + lane]);
                bf16x8 b3 = {0, 0, 0, 0, 0, 0, 0, 0};
                if (g == 0) b3 = *reinterpret_cast<const bf16x8*>(&wlds3[16 * n + lr]);

                f32x4 acc = {bias_r[n], bias_r[n], bias_r[n], bias_r[n]};
                acc = __builtin_amdgcn_mfma_f32_16x16x32_bf16(a[0], bfr[0], acc, 0, 0, 0);
                acc = __builtin_amdgcn_mfma_f32_16x16x32_bf16(a[1], bfr[1], acc, 0, 0, 0);
                acc = __builtin_amdgcn_mfma_f32_16x16x32_bf16(a[2], bfr[2], acc, 0, 0, 0);
                acc = __builtin_amdgcn_mfma_f32_16x16x32_bf16(a3,  b3,     acc, 0, 0, 0);
                #pragma unroll
                for (int r = 0; r < 4; ++r)
                    scp[r] = fmaf(fast_tanh(acc[r]), cw_r[n], scp[r]);
            }
            // reduce over the 16 col-lanes; lane lr==0 holds score of row 4g+r
            #pragma unroll
            for (int r = 0; r < 4; ++r) {
                float v = scp[r];
                v += __shfl_xor(v, 1);
                v += __shfl_xor(v, 2);
                v += __shfl_xor(v, 4);
                v += __shfl_xor(v, 8);
                if (lr == 0)
                    wexp[16 * wid + 4 * g + r] = __expf(fast_tanh(v));
            }
        }
        __syncthreads();   // B1: wexp ready

        // ---- 3. denominator partials (threads 0..7 own column b = tid) ----
        if (tid < NBCOL) {
            float d = 0.0f;
            #pragma unroll
            for (int s = 0; s < SCH; ++s) d += wexp[s * NBCOL + tid];
            dreg += d;
        }

        // ---- 4. pooled numerator: acc[b,d] += sum_s w[s,b] * f[s,b,d] ----
        if (pact) {
            #pragma unroll
            for (int s = 0; s < SCH; ++s) {
                const float w = wexp[s * NBCOL + pb];
                const unsigned int u =
                    *reinterpret_cast<const unsigned int*>(&fs[cur][s * NBCOL + pb][pd]);
                acc0 = fmaf(w, bf2f_lo(u), acc0);
                acc1 = fmaf(w, bf2f_hi(u), acc1);
            }
        }

        // ---- 5. write prefetched chunk into the other buffer ----
        if (pf) {
            #pragma unroll
            for (int r = 0; r < 7; ++r) {
                const int i = tid + 512 * r;
                if (r < 6 || tid < CH_F4 - 512 * 6) {
                    const int s = i / 200, piece = i - 200 * s;
                    const int bl = piece / 25, c4 = piece - 25 * bl;
                    uint2 pk;
                    pk.x = (unsigned)f2bf_u(rv[r].x) | ((unsigned)f2bf_u(rv[r].y) << 16);
                    pk.y = (unsigned)f2bf_u(rv[r].z) | ((unsigned)f2bf_u(rv[r].w) << 16);
                    *reinterpret_cast<uint2*>(&fs[cur ^ 1][s * NBCOL + bl][4 * c4]) = pk;
                }
            }
        }
        __syncthreads();   // B2: next buffer complete; wexp free for reuse
        cur ^= 1;
    }

    // ---- epilogue: normalize and write pooled ----
    if (tid < NBCOL) den_s[tid] = dreg;
    __syncthreads();
    if (pact) {
        const float rd = 1.0f / den_s[pb];
        float2 o;
        o.x = acc0 * rd;
        o.y = acc1 * rd;
        *reinterpret_cast<float2*>(&out[(size_t)(b0 + pb) * DD + pd]) = o;
    }
}

extern "C" void kernel_launch(void* const* d_in, const int* in_sizes, int n_in,
                              void* d_out, int out_size, void* d_ws, size_t ws_size,
                              hipStream_t stream) {
    const float* f    = (const float*)d_in[0];   // [256, 4096, 100]
    const float* h    = (const float*)d_in[1];   // [2, 4096, 50]
    const float* W    = (const float*)d_in[2];   // [100, 100]
    const float* bias = (const float*)d_in[3];   // [1, 100]
    const float* cw   = (const float*)d_in[4];   // [100, 1]
    float* out = (float*)d_out;                  // [pooled 409600 | h 409600]

    uint4* wsf = (uint4*)d_ws;                   // 28,672 B

    prep_wfrag<<<7, 256, 0, stream>>>(W, wsf);
    fused_sent_attn<<<BATCH / NBCOL, 512, 0, stream>>>(f, wsf, bias, cw, h, out);
}

// Round 6
// 128.773 us; speedup vs baseline: 1.9542x; 1.5984x over previous
//
#include <hip/hip_runtime.h>
#include <hip/hip_bf16.h>

#define SEQ 256
#define BATCH 4096
#define DD 100
#define SB (BATCH * DD)             // floats between s-planes
#define NBCOL 8                     // batch columns per block
#define SCH 8                       // s per chunk
#define NCHUNK (SEQ / SCH)          // 32
#define ROWS (SCH * NBCOL)          // 64 rows per chunk (row = s_local*8 + b_local)
#define SLAB_B (NBCOL * DD * 4)     // 3200 bytes per s-slab (contiguous in global AND LDS)
#define CH_BYTES (ROWS * DD * 4)    // 25600 bytes per chunk
#define CH_INSTR (CH_BYTES / 1024)  // 25 wave-instructions of 1 KB (64 lanes x 16 B)

typedef __attribute__((ext_vector_type(8))) short bf16x8;
typedef __attribute__((ext_vector_type(4))) float f32x4;

__device__ __forceinline__ short f2bf(float x) {
    __hip_bfloat16 hv = __float2bfloat16(x);
    return *reinterpret_cast<short*>(&hv);
}
__device__ __forceinline__ float fast_tanh(float x) {
    float ax = fabsf(x);
    float e  = __expf(-2.0f * ax);
    float t  = (1.0f - e) * __builtin_amdgcn_rcpf(1.0f + e);
    return copysignf(t, x);
}

// ---- prep: pack W [DD x DD] fp32 -> MFMA B-fragments (bf16, zero-padded) ----
// frag (n,t): cols [16n,16n+16), k [32t,32t+32). lane l: col = 16n+(l&15),
// k = 32t + 8*(l>>4) + e. Layout verified rounds 2-5.
__global__ void prep_wfrag(const float* __restrict__ W, uint4* __restrict__ wsf) {
    const int idx = blockIdx.x * 256 + threadIdx.x;
    if (idx >= 28 * 64) return;
    const int l  = idx & 63;
    const int ft = idx >> 6;
    const int t  = ft & 3;
    const int n  = ft >> 2;
    const int col   = 16 * n + (l & 15);
    const int kbase = 32 * t + 8 * (l >> 4);
    unsigned short v[8];
    #pragma unroll
    for (int e = 0; e < 8; ++e) {
        const int k = kbase + e;
        const float w = (col < DD && k < DD) ? W[k * DD + col] : 0.0f;
        v[e] = (unsigned short)f2bf(w);
    }
    uint4 u;
    u.x = (unsigned)v[0] | ((unsigned)v[1] << 16);
    u.y = (unsigned)v[2] | ((unsigned)v[3] << 16);
    u.z = (unsigned)v[4] | ((unsigned)v[5] << 16);
    u.w = (unsigned)v[6] | ((unsigned)v[7] << 16);
    wsf[ft * 64 + l] = u;
}

// Issue the 25 x 1KB direct global->LDS loads for chunk starting at s-plane s0.
// LDS dest per lane = lbase + q*1024 + lane*16 (wave-uniform base + lane*16,
// required by HW); global src per-lane, crossing 3200B slab boundaries freely.
__device__ __forceinline__ void stage_chunk(const float* __restrict__ f,
                                            int s0, int b0, float* lbase,
                                            int wid, int lane) {
    #pragma unroll
    for (int r = 0; r < 7; ++r) {
        const int q = wid + 4 * r;              // wave-uniform slot
        if (q < CH_INSTR) {
            const int L   = (q << 10) + (lane << 4);   // byte offset in chunk
            const int s   = L / SLAB_B;
            const int rem = L - s * SLAB_B;
            const float* gp = f + (size_t)(s0 + s) * SB + (size_t)b0 * DD + (rem >> 2);
            __builtin_amdgcn_global_load_lds(
                (const __attribute__((address_space(1))) void*)gp,
                (__attribute__((address_space(3))) void*)((char*)lbase + L),
                16, 0, 0);
        }
    }
}

__global__ __launch_bounds__(256, 2)
void fused_sent_attn(const float* __restrict__ f,     // [SEQ, BATCH, DD]
                     const uint4* __restrict__ wsf,   // packed W frags (28*64)
                     const float* __restrict__ bias,  // [DD]
                     const float* __restrict__ cw,    // [DD]
                     const float* __restrict__ h,     // [2, BATCH, 50]
                     float* __restrict__ out)         // [pooled | h]
{
    __shared__ float fs[2][ROWS * DD];   // 2 x 25,600 B, f32, linear slab layout
    __shared__ uint4 wlds[21 * 64];      // 21,504 B (t = 0..2 frags)
    __shared__ uint4 wlds3[7 * 16];      // 1,792 B  (t = 3, lanes 0..15)
    __shared__ float wexp[ROWS];         // e^tanh(score) per row
    __shared__ float den_s[NBCOL];

    const int tid  = threadIdx.x;
    const int lane = tid & 63;
    const int wid  = tid >> 6;
    const int lr   = lane & 15;
    const int g    = lane >> 4;
    const int b0   = blockIdx.x * NBCOL;

    // ---- prologue: W frags -> LDS ----
    for (int i = tid; i < 21 * 64; i += 256) {
        const int n = i / 192, rem = i % 192;
        wlds[i] = wsf[(4 * n + rem / 64) * 64 + (rem & 63)];
    }
    if (tid < 7 * 16) wlds3[tid] = wsf[(4 * (tid >> 4) + 3) * 64 + (tid & 15)];

    float bias_r[7], cw_r[7];
    #pragma unroll
    for (int n = 0; n < 7; ++n) {
        const int c = 16 * n + lr;
        bias_r[n] = (c < DD) ? bias[c] : 0.0f;
        cw_r[n]   = (c < DD) ? cw[c]   : 0.0f;
    }

    // h passthrough: this block's 8 columns, both halves (contiguous 400-f32 runs)
    {
        const size_t obase = (size_t)BATCH * DD;
        const size_t HB = (size_t)BATCH * 50;
        for (int i = tid; i < 2 * NBCOL * 50; i += 256) {
            const int half = i / (NBCOL * 50);
            const int rem  = i - half * (NBCOL * 50);
            const size_t src = half * HB + (size_t)b0 * 50 + rem;
            out[obase + src] = h[src];
        }
    }

    // ---- stage chunk 0 and wait ----
    stage_chunk(f, 0, b0, fs[0], wid, lane);
    asm volatile("s_waitcnt vmcnt(0) lgkmcnt(0)" ::: "memory");
    __builtin_amdgcn_s_barrier();
    __builtin_amdgcn_sched_barrier(0);

    // pooling ownership: 200 threads, (col pb, f32x4 quad q4)
    const int pb = tid / 25, q4 = tid % 25;
    const bool pact = (tid < 200);
    f32x4 pacc = {0.0f, 0.0f, 0.0f, 0.0f};
    float dreg = 0.0f;

    int cur = 0;
    for (int jc = 0; jc < NCHUNK; ++jc) {
        // ---- 1. issue next chunk's direct-to-LDS loads (cannot be sunk) ----
        if (jc + 1 < NCHUNK)
            stage_chunk(f, (jc + 1) * SCH, b0, fs[cur ^ 1], wid, lane);

        // ---- 2. scores: wave owns rows 16*wid..16*wid+15 of this chunk ----
        {
            const float* rp = &fs[cur][(16 * wid + lr) * DD];
            bf16x8 a[4];
            #pragma unroll
            for (int t = 0; t < 3; ++t) {
                const float4 u0 = *reinterpret_cast<const float4*>(rp + 32 * t + 8 * g);
                const float4 u1 = *reinterpret_cast<const float4*>(rp + 32 * t + 8 * g + 4);
                bf16x8 av;
                av[0] = f2bf(u0.x); av[1] = f2bf(u0.y);
                av[2] = f2bf(u0.z); av[3] = f2bf(u0.w);
                av[4] = f2bf(u1.x); av[5] = f2bf(u1.y);
                av[6] = f2bf(u1.z); av[7] = f2bf(u1.w);
                a[t] = av;
            }
            bf16x8 a3 = {0, 0, 0, 0, 0, 0, 0, 0};
            if (g == 0) {
                const float4 u0 = *reinterpret_cast<const float4*>(rp + 96);
                a3[0] = f2bf(u0.x); a3[1] = f2bf(u0.y);
                a3[2] = f2bf(u0.z); a3[3] = f2bf(u0.w);
            }
            a[3] = a3;

            float scp[4] = {0, 0, 0, 0};
            #pragma unroll
            for (int n = 0; n < 7; ++n) {
                bf16x8 bfr[3];
                #pragma unroll
                for (int t = 0; t < 3; ++t)
                    bfr[t] = *reinterpret_cast<const bf16x8*>(&wlds[(3 * n + t) * 64 + lane]);
                bf16x8 b3 = {0, 0, 0, 0, 0, 0, 0, 0};
                if (g == 0) b3 = *reinterpret_cast<const bf16x8*>(&wlds3[16 * n + lr]);

                f32x4 acc = {bias_r[n], bias_r[n], bias_r[n], bias_r[n]};
                acc = __builtin_amdgcn_mfma_f32_16x16x32_bf16(a[0], bfr[0], acc, 0, 0, 0);
                acc = __builtin_amdgcn_mfma_f32_16x16x32_bf16(a[1], bfr[1], acc, 0, 0, 0);
                acc = __builtin_amdgcn_mfma_f32_16x16x32_bf16(a[2], bfr[2], acc, 0, 0, 0);
                acc = __builtin_amdgcn_mfma_f32_16x16x32_bf16(a[3], b3,     acc, 0, 0, 0);
                #pragma unroll
                for (int r = 0; r < 4; ++r)
                    scp[r] = fmaf(fast_tanh(acc[r]), cw_r[n], scp[r]);
            }
            #pragma unroll
            for (int r = 0; r < 4; ++r) {
                float v = scp[r];
                v += __shfl_xor(v, 1);
                v += __shfl_xor(v, 2);
                v += __shfl_xor(v, 4);
                v += __shfl_xor(v, 8);
                if (lr == 0)
                    wexp[16 * wid + 4 * g + r] = __expf(fast_tanh(v));
            }
        }
        // B1: wexp ready; staged vmem loads deliberately stay in flight
        asm volatile("s_waitcnt lgkmcnt(0)" ::: "memory");
        __builtin_amdgcn_s_barrier();
        __builtin_amdgcn_sched_barrier(0);

        // ---- 3. pooled numerator (+ denominator in threads 200..207) ----
        if (pact) {
            #pragma unroll
            for (int s = 0; s < SCH; ++s) {
                const float w = wexp[s * NBCOL + pb];
                const f32x4 v = *reinterpret_cast<const f32x4*>(
                    &fs[cur][(s * NBCOL + pb) * DD + 4 * q4]);
                pacc.x = fmaf(w, v.x, pacc.x);
                pacc.y = fmaf(w, v.y, pacc.y);
                pacc.z = fmaf(w, v.z, pacc.z);
                pacc.w = fmaf(w, v.w, pacc.w);
            }
        } else if (tid < 208) {
            const int bcol = tid - 200;
            float d = 0.0f;
            #pragma unroll
            for (int s = 0; s < SCH; ++s) d += wexp[s * NBCOL + bcol];
            dreg += d;
        }

        // B2: next chunk fully landed in LDS; all reads of fs[cur] complete
        asm volatile("s_waitcnt vmcnt(0) lgkmcnt(0)" ::: "memory");
        __builtin_amdgcn_s_barrier();
        __builtin_amdgcn_sched_barrier(0);
        cur ^= 1;
    }

    // ---- epilogue: normalize and write pooled ----
    if (tid >= 200 && tid < 208) den_s[tid - 200] = dreg;
    __syncthreads();
    if (pact) {
        const float rd = 1.0f / den_s[pb];
        float4 o;
        o.x = pacc.x * rd;
        o.y = pacc.y * rd;
        o.z = pacc.z * rd;
        o.w = pacc.w * rd;
        *reinterpret_cast<float4*>(&out[(size_t)(b0 + pb) * DD + 4 * q4]) = o;
    }
}

extern "C" void kernel_launch(void* const* d_in, const int* in_sizes, int n_in,
                              void* d_out, int out_size, void* d_ws, size_t ws_size,
                              hipStream_t stream) {
    const float* f    = (const float*)d_in[0];   // [256, 4096, 100]
    const float* h    = (const float*)d_in[1];   // [2, 4096, 50]
    const float* W    = (const float*)d_in[2];   // [100, 100]
    const float* bias = (const float*)d_in[3];   // [1, 100]
    const float* cw   = (const float*)d_in[4];   // [100, 1]
    float* out = (float*)d_out;                  // [pooled 409600 | h 409600]

    uint4* wsf = (uint4*)d_ws;                   // 28,672 B

    prep_wfrag<<<7, 256, 0, stream>>>(W, wsf);
    fused_sent_attn<<<BATCH / NBCOL, 256, 0, stream>>>(f, wsf, bias, cw, h, out);
}

// Round 7
// 118.825 us; speedup vs baseline: 2.1178x; 1.0837x over previous
//
#include <hip/hip_runtime.h>
#include <hip/hip_bf16.h>

#define SEQ 256
#define BATCH 4096
#define DD 100
#define SB (BATCH * DD)             // floats between s-planes
#define NBCOL 8                     // batch columns per block
#define SCH 8                       // s-planes per chunk
#define NCHUNK (SEQ / SCH)          // 32
#define ROWS (SCH * NBCOL)          // 64 rows per chunk (row = s_local*8 + b_local)
#define SLAB_B (NBCOL * DD * 4)     // 3200 B per s-slab (contiguous global AND LDS)
#define CH_BYTES (ROWS * DD * 4)    // 25600 B per chunk
#define CH_INSTR (CH_BYTES / 1024)  // 25 x 1KB wave-instructions

typedef __attribute__((ext_vector_type(8))) short bf16x8;
typedef __attribute__((ext_vector_type(4))) float f32x4;
typedef __attribute__((ext_vector_type(4))) unsigned u32x4;

#define WAIT_VM6  asm volatile("s_waitcnt vmcnt(6)" ::: "memory")
#define WAIT_VM0  asm volatile("s_waitcnt vmcnt(0)" ::: "memory")
#define WAIT_LGKM asm volatile("s_waitcnt lgkmcnt(0)" ::: "memory")

__device__ __forceinline__ short f2bf(float x) {
    __hip_bfloat16 hv = __float2bfloat16(x);
    return *reinterpret_cast<short*>(&hv);
}
// accurate tanh (outer only; 4 uses/wave/chunk)
__device__ __forceinline__ float fast_tanh(float x) {
    float ax = fabsf(x);
    float e  = __expf(-2.0f * ax);
    float t  = (1.0f - e) * __builtin_amdgcn_rcpf(1.0f + e);
    return copysignf(t, x);
}
// Pade(3,2) tanh, clamped: max abs err ~0.025 near |x|~2 (inner u-activations;
// error budget analysis: contributes <1e-2 to final absmax vs 9.2e-2 threshold)
__device__ __forceinline__ float pade_tanh(float x) {
    const float x2  = x * x;
    const float num = x * (27.0f + x2);
    const float den = fmaf(9.0f, x2, 27.0f);
    const float t   = num * __builtin_amdgcn_rcpf(den);
    return fminf(1.0f, fmaxf(-1.0f, t));
}
// (bf16(hi)<<16) | bf16(lo), truncating round — one v_perm_b32
__device__ __forceinline__ unsigned pack_bf2(float lo, float hi) {
    return __builtin_amdgcn_perm(__builtin_bit_cast(unsigned, hi),
                                 __builtin_bit_cast(unsigned, lo),
                                 0x07060302u);
}

// ---- prep: pack W [DD x DD] fp32 -> MFMA B-fragments (bf16, zero-padded) ----
// frag (n,t): cols [16n,16n+16), k [32t,32t+32). lane l: col = 16n+(l&15),
// k = 32t + 8*(l>>4) + e. Layout verified rounds 2-6.
__global__ void prep_wfrag(const float* __restrict__ W, uint4* __restrict__ wsf) {
    const int idx = blockIdx.x * 256 + threadIdx.x;
    if (idx >= 28 * 64) return;
    const int l  = idx & 63;
    const int ft = idx >> 6;
    const int t  = ft & 3;
    const int n  = ft >> 2;
    const int col   = 16 * n + (l & 15);
    const int kbase = 32 * t + 8 * (l >> 4);
    unsigned short v[8];
    #pragma unroll
    for (int e = 0; e < 8; ++e) {
        const int k = kbase + e;
        const float w = (col < DD && k < DD) ? W[k * DD + col] : 0.0f;
        v[e] = (unsigned short)f2bf(w);
    }
    uint4 u;
    u.x = (unsigned)v[0] | ((unsigned)v[1] << 16);
    u.y = (unsigned)v[2] | ((unsigned)v[3] << 16);
    u.z = (unsigned)v[4] | ((unsigned)v[5] << 16);
    u.w = (unsigned)v[6] | ((unsigned)v[7] << 16);
    wsf[ft * 64 + l] = u;
}

// 25 x 1KB direct global->LDS loads for the chunk at s-plane s0.
// Slot q -> LDS bytes [q*1024, q*1024+1024); wave w issues slots {w, w+4, ...}:
// wave 0 issues 7, waves 1-3 issue 6  (counted-vmcnt math relies on this).
__device__ __forceinline__ void stage_chunk(const float* __restrict__ f,
                                            int s0, int b0, float* lbase,
                                            int wid, int lane) {
    #pragma unroll
    for (int r = 0; r < 7; ++r) {
        const int q = wid + 4 * r;
        if (q < CH_INSTR) {
            const int L   = (q << 10) + (lane << 4);
            const int s   = L / SLAB_B;
            const int rem = L - s * SLAB_B;
            const float* gp = f + (size_t)(s0 + s) * SB + (size_t)b0 * DD + (rem >> 2);
            __builtin_amdgcn_global_load_lds(
                (const __attribute__((address_space(1))) void*)gp,
                (__attribute__((address_space(3))) void*)((char*)lbase + L),
                16, 0, 0);
        }
    }
}

__global__ __launch_bounds__(256, 2)
void fused_sent_attn(const float* __restrict__ f,     // [SEQ, BATCH, DD]
                     const uint4* __restrict__ wsf,   // packed W frags (28*64)
                     const float* __restrict__ bias,  // [DD]
                     const float* __restrict__ cw,    // [DD]
                     const float* __restrict__ h,     // [2, BATCH, 50]
                     float* __restrict__ out)         // [pooled | h]
{
    __shared__ __align__(16) float fs[3][ROWS * DD];  // 76,800 B triple buffer
    __shared__ float wexp[ROWS];
    __shared__ float den_s[NBCOL];

    const int tid  = threadIdx.x;
    const int lane = tid & 63;
    const int wid  = tid >> 6;
    const int lr   = lane & 15;
    const int g    = lane >> 4;
    const int b0   = blockIdx.x * NBCOL;

    // ---- prologue: bias/cw regs, h passthrough (stores drained below) ----
    float bias_r[7], cw_r[7];
    #pragma unroll
    for (int n = 0; n < 7; ++n) {
        const int c = 16 * n + lr;
        bias_r[n] = (c < DD) ? bias[c] : 0.0f;
        cw_r[n]   = (c < DD) ? cw[c]   : 0.0f;
    }
    {   // h: this block's 8 columns, both halves; 200 x float4
        const size_t obase = (size_t)BATCH * DD;
        const size_t HB = (size_t)BATCH * 50;
        if (tid < 200) {
            const int half = tid / 100, rem = tid - 100 * half;
            const float4* hs = reinterpret_cast<const float4*>(h + half * HB + (size_t)b0 * 50);
            float4* od = reinterpret_cast<float4*>(out + obase + half * HB + (size_t)b0 * 50);
            od[rem] = hs[rem];
        }
    }

    // ---- W fragments -> registers (wave-invariant, 112 VGPR) ----
    bf16x8 wr[28];
    #pragma unroll
    for (int i = 0; i < 28; ++i)
        wr[i] = *reinterpret_cast<const bf16x8*>(&wsf[i * 64 + lane]);
    WAIT_VM0;                       // wr + h-stores + bias/cw drained

    // ---- pipeline prologue: chunks 0,1 in flight; wait chunk 0 ----
    stage_chunk(f, 0,   b0, fs[0], wid, lane);
    stage_chunk(f, SCH, b0, fs[1], wid, lane);
    WAIT_VM6;                       // chunk0 landed (wave0 over-waits 1 load: ok)
    __builtin_amdgcn_s_barrier();
    __builtin_amdgcn_sched_barrier(0);

    // pooling ownership: 200 threads x (col pb, float4-quad q4); 8 denom threads
    const int pb = tid / 25, q4 = tid % 25;
    const bool pact = (tid < 200);
    f32x4 pacc = {0.0f, 0.0f, 0.0f, 0.0f};
    float dreg = 0.0f;

    int cur = 0;
    for (int jc = 0; jc < NCHUNK; ++jc) {
        const int nxt2 = (cur + 2 >= 3) ? cur - 1 : cur + 2;

        // ---- 1. issue chunk jc+2 (stays in flight across this iteration) ----
        if (jc + 2 < NCHUNK)
            stage_chunk(f, (jc + 2) * SCH, b0, fs[nxt2], wid, lane);

        // ---- 2. scores: wave owns rows 16*wid..16*wid+15 of chunk jc ----
        {
            const float* rp = &fs[cur][(16 * wid + lr) * DD];
            bf16x8 a[4];
            #pragma unroll
            for (int t = 0; t < 3; ++t) {
                const float4 u0 = *reinterpret_cast<const float4*>(rp + 32 * t + 8 * g);
                const float4 u1 = *reinterpret_cast<const float4*>(rp + 32 * t + 8 * g + 4);
                u32x4 pk = {pack_bf2(u0.x, u0.y), pack_bf2(u0.z, u0.w),
                            pack_bf2(u1.x, u1.y), pack_bf2(u1.z, u1.w)};
                a[t] = __builtin_bit_cast(bf16x8, pk);
            }
            {
                u32x4 pk = {0u, 0u, 0u, 0u};
                if (g == 0) {
                    const float4 u0 = *reinterpret_cast<const float4*>(rp + 96);
                    pk.x = pack_bf2(u0.x, u0.y);
                    pk.y = pack_bf2(u0.z, u0.w);
                }
                a[3] = __builtin_bit_cast(bf16x8, pk);
            }

            float scp[4] = {0, 0, 0, 0};
            #pragma unroll
            for (int n = 0; n < 7; ++n) {
                f32x4 acc = {bias_r[n], bias_r[n], bias_r[n], bias_r[n]};
                acc = __builtin_amdgcn_mfma_f32_16x16x32_bf16(a[0], wr[4 * n + 0], acc, 0, 0, 0);
                acc = __builtin_amdgcn_mfma_f32_16x16x32_bf16(a[1], wr[4 * n + 1], acc, 0, 0, 0);
                acc = __builtin_amdgcn_mfma_f32_16x16x32_bf16(a[2], wr[4 * n + 2], acc, 0, 0, 0);
                acc = __builtin_amdgcn_mfma_f32_16x16x32_bf16(a[3], wr[4 * n + 3], acc, 0, 0, 0);
                #pragma unroll
                for (int r = 0; r < 4; ++r)
                    scp[r] = fmaf(pade_tanh(acc[r]), cw_r[n], scp[r]);
            }
            #pragma unroll
            for (int r = 0; r < 4; ++r) {
                float v = scp[r];
                v += __shfl_xor(v, 1);
                v += __shfl_xor(v, 2);
                v += __shfl_xor(v, 4);
                v += __shfl_xor(v, 8);
                if (lr == 0)
                    wexp[16 * wid + 4 * g + r] = __expf(fast_tanh(v));
            }
        }
        WAIT_LGKM;                        // wexp ds_writes done
        __builtin_amdgcn_s_barrier();     // B1: wexp visible to all
        __builtin_amdgcn_sched_barrier(0);

        // ---- 3. pooled numerator + denominator ----
        if (pact) {
            #pragma unroll
            for (int s = 0; s < SCH; ++s) {
                const float w = wexp[s * NBCOL + pb];
                const f32x4 v = *reinterpret_cast<const f32x4*>(
                    &fs[cur][(s * NBCOL + pb) * DD + 4 * q4]);
                pacc.x = fmaf(w, v.x, pacc.x);
                pacc.y = fmaf(w, v.y, pacc.y);
                pacc.z = fmaf(w, v.z, pacc.z);
                pacc.w = fmaf(w, v.w, pacc.w);
            }
        } else if (tid < 208) {
            const int bcol = tid - 200;
            float d = 0.0f;
            #pragma unroll
            for (int s = 0; s < SCH; ++s) d += wexp[s * NBCOL + bcol];
            dreg += d;
        }

        // ---- 4. wait for chunk jc+1 ONLY (chunk jc+2's loads stay in flight) ----
        if (jc + 2 < NCHUNK) { WAIT_VM6; } else { WAIT_VM0; }
        __builtin_amdgcn_s_barrier();     // B2: next chunk ready; pool reads done
        __builtin_amdgcn_sched_barrier(0);
        cur = (cur + 1 >= 3) ? 0 : cur + 1;
    }

    // ---- epilogue: normalize and write pooled ----
    if (tid >= 200 && tid < 208) den_s[tid - 200] = dreg;
    __syncthreads();
    if (pact) {
        const float rd = 1.0f / den_s[pb];
        float4 o;
        o.x = pacc.x * rd;
        o.y = pacc.y * rd;
        o.z = pacc.z * rd;
        o.w = pacc.w * rd;
        *reinterpret_cast<float4*>(&out[(size_t)(b0 + pb) * DD + 4 * q4]) = o;
    }
}

extern "C" void kernel_launch(void* const* d_in, const int* in_sizes, int n_in,
                              void* d_out, int out_size, void* d_ws, size_t ws_size,
                              hipStream_t stream) {
    const float* f    = (const float*)d_in[0];   // [256, 4096, 100]
    const float* h    = (const float*)d_in[1];   // [2, 4096, 50]
    const float* W    = (const float*)d_in[2];   // [100, 100]
    const float* bias = (const float*)d_in[3];   // [1, 100]
    const float* cw   = (const float*)d_in[4];   // [100, 1]
    float* out = (float*)d_out;                  // [pooled 409600 | h 409600]

    uint4* wsf = (uint4*)d_ws;                   // 28,672 B

    prep_wfrag<<<7, 256, 0, stream>>>(W, wsf);
    fused_sent_attn<<<BATCH / NBCOL, 256, 0, stream>>>(f, wsf, bias, cw, h, out);
}